// Round 1
// baseline (1403.354 us; speedup 1.0000x reference)
//
#include <hip/hip_runtime.h>
#include <cstdint>

// Problem constants (validated against in_sizes at launch)
// N=50000 nodes, E=1.6M edges, IN=128, H=64, OUT=32, R=8
#define HDIM 64
#define ODIM 32
#define NEG_SLOPE 0.2f

// ---------------------------------------------------------------------------
// CSR build
// ---------------------------------------------------------------------------
__global__ __launch_bounds__(256) void count_deg_kernel(
    const int* __restrict__ dst, int* __restrict__ deg, int E) {
  int e = blockIdx.x * 256 + threadIdx.x;
  if (e < E) atomicAdd(&deg[dst[e]], 1);
}

__global__ __launch_bounds__(1024) void scan_kernel(
    const int* __restrict__ deg, int* __restrict__ row_ptr, int n) {
  __shared__ int sdata[1024];
  __shared__ int s_carry;
  if (threadIdx.x == 0) s_carry = 0;
  __syncthreads();
  for (int base = 0; base < n; base += 1024) {
    int i = base + threadIdx.x;
    int v = (i < n) ? deg[i] : 0;
    sdata[threadIdx.x] = v;
    __syncthreads();
    for (int off = 1; off < 1024; off <<= 1) {
      int tv = (threadIdx.x >= (unsigned)off) ? sdata[threadIdx.x - off] : 0;
      __syncthreads();
      sdata[threadIdx.x] += tv;
      __syncthreads();
    }
    int carry = s_carry;
    if (i < n) row_ptr[i + 1] = sdata[threadIdx.x] + carry;
    __syncthreads();
    if (threadIdx.x == 1023) s_carry = carry + sdata[1023];
    __syncthreads();
  }
  if (threadIdx.x == 0) row_ptr[0] = 0;
}

// pack src (17 bits would overflow; N=50000 < 65536 so 16 bits) | etype<<16
__global__ __launch_bounds__(256) void scatter_kernel(
    const int* __restrict__ src, const int* __restrict__ dst,
    const int* __restrict__ etype, const int* __restrict__ row_ptr,
    int* __restrict__ fill, int* __restrict__ edges, int E) {
  int e = blockIdx.x * 256 + threadIdx.x;
  if (e < E) {
    int d = dst[e];
    int pos = row_ptr[d] + atomicAdd(&fill[d], 1);
    edges[pos] = src[e] | (etype[e] << 16);
  }
}

// ---------------------------------------------------------------------------
// Per-relation transform: t[r,n,:] = f[n,:] @ W[r]  (+ aq/ak epilogue)
//   f: [N, CIN]  W: [R, CIN, 64]  t: [R, N, 64]  aq/ak: [R, N]
// Block: 256 threads = 4 waves; each wave handles 8 nodes x 64 outputs.
// W staged in LDS in chunked [i/4][o][4] layout -> conflict-free ds_read_b128.
// ---------------------------------------------------------------------------
template <int CIN>
__global__ __launch_bounds__(256) void transform_kernel(
    const float* __restrict__ f, const float* __restrict__ W,
    const float* __restrict__ q, const float* __restrict__ k,
    float* __restrict__ t, float* __restrict__ aq, float* __restrict__ ak,
    int N) {
  constexpr int NT = 32;  // nodes per block
  __shared__ float Wl[CIN * 64];   // chunked: [(i>>2)][o][i&3]
  __shared__ float Fl[NT * CIN];   // [n][i]
  __shared__ float qk[128];

  const int r = blockIdx.y;
  const int n0 = blockIdx.x * NT;

  // stage W[r] (global-coalesced reads)
  for (int idx = threadIdx.x; idx < CIN * 64; idx += 256) {
    int i = idx >> 6, o = idx & 63;
    Wl[(((i >> 2) * 64) + o) * 4 + (i & 3)] = W[((size_t)r * CIN + i) * 64 + o];
  }
  if (threadIdx.x < 64) {
    qk[threadIdx.x] = q[threadIdx.x];
    qk[64 + threadIdx.x] = k[threadIdx.x];
  }
  // stage f tile (global-coalesced)
  for (int idx = threadIdx.x; idx < NT * CIN; idx += 256) {
    int n = idx / CIN, i = idx % CIN;
    int gn = n0 + n;
    Fl[idx] = (gn < N) ? f[(size_t)gn * CIN + i] : 0.f;
  }
  __syncthreads();

  const int o = threadIdx.x & 63;
  const int nsub = threadIdx.x >> 6;  // 0..3, uniform per wave

  float acc[8];
#pragma unroll
  for (int j = 0; j < 8; j++) acc[j] = 0.f;

#pragma unroll 2
  for (int c = 0; c < CIN / 4; c++) {
    float4 w4 = *(const float4*)&Wl[(c * 64 + o) * 4];
#pragma unroll
    for (int j = 0; j < 8; j++) {
      const int n = nsub * 8 + j;
      float4 f4 = *(const float4*)&Fl[n * CIN + 4 * c];  // LDS broadcast
      acc[j] = fmaf(w4.x, f4.x, acc[j]);
      acc[j] = fmaf(w4.y, f4.y, acc[j]);
      acc[j] = fmaf(w4.z, f4.z, acc[j]);
      acc[j] = fmaf(w4.w, f4.w, acc[j]);
    }
  }

  const float qo = qk[o];
  const float ko = qk[64 + o];
#pragma unroll
  for (int j = 0; j < 8; j++) {
    const int gn = n0 + nsub * 8 + j;
    const bool valid = gn < N;
    if (valid) t[((size_t)r * N + gn) * 64 + o] = acc[j];
    float vq = acc[j] * qo;
    float vk = acc[j] * ko;
#pragma unroll
    for (int d = 32; d > 0; d >>= 1) {
      vq += __shfl_down(vq, d, 64);
      vk += __shfl_down(vk, d, 64);
    }
    if (o == 0 && valid) {
      aq[(size_t)r * N + gn] = vq;
      ak[(size_t)r * N + gn] = vk;
    }
  }
}

// ---------------------------------------------------------------------------
// Aggregate: one wave per destination node, online softmax over its in-edges.
// lane = output channel. out[n,:] = relu( sum_e alpha_e * t[r_e, src_e, :] + b )
// ---------------------------------------------------------------------------
__global__ __launch_bounds__(256) void aggregate_kernel(
    const int* __restrict__ row_ptr, const int* __restrict__ edges,
    const float* __restrict__ t, const float* __restrict__ aq,
    const float* __restrict__ ak, const float* __restrict__ bias,
    float* __restrict__ out, int N) {
  const int wid = (blockIdx.x * 256 + threadIdx.x) >> 6;  // node id
  const int o = threadIdx.x & 63;
  if (wid >= N) return;
  const int beg = row_ptr[wid];
  const int end = row_ptr[wid + 1];

  float m = -1e30f, s = 0.f, acc = 0.f;
  for (int e = beg; e < end; e++) {
    const int packed = edges[e];
    const int src = packed & 0xFFFF;
    const int r = packed >> 16;
    const float tv = t[((size_t)r * N + src) * 64 + o];  // coalesced 256B
    float a = aq[(size_t)r * N + wid] + ak[(size_t)r * N + src];
    a = (a >= 0.f) ? a : NEG_SLOPE * a;
    const float nm = fmaxf(m, a);
    const float scale = __expf(m - nm);  // m=-1e30 -> 0; m==nm -> 1
    const float p = __expf(a - nm);
    s = s * scale + p;
    acc = acc * scale + p * tv;
    m = nm;
  }
  const float res = acc / (s + 1e-16f) + bias[o];
  out[(size_t)wid * 64 + o] = fmaxf(res, 0.f);  // relu (all 3 RGAT layers)
}

// ---------------------------------------------------------------------------
// Final linear: out[n,:ODIM] = (f[n,:64] @ W + b) * scale
// ---------------------------------------------------------------------------
__global__ __launch_bounds__(256) void linear_kernel(
    const float* __restrict__ f, const float* __restrict__ W,
    const float* __restrict__ b, float* __restrict__ out, float scale, int N) {
  __shared__ float Wl[HDIM * ODIM];
  __shared__ float bl[ODIM];
  for (int i = threadIdx.x; i < HDIM * ODIM; i += 256) Wl[i] = W[i];
  if (threadIdx.x < ODIM) bl[threadIdx.x] = b[threadIdx.x];
  __syncthreads();
  const int tid = blockIdx.x * 256 + threadIdx.x;
  const int n = tid >> 5;
  const int o = tid & 31;
  if (n >= N) return;
  const float* fr = f + (size_t)n * HDIM;
  float acc = 0.f;
#pragma unroll
  for (int i = 0; i < HDIM; i++) acc = fmaf(fr[i], Wl[i * ODIM + o], acc);
  out[(size_t)n * ODIM + o] = (acc + bl[o]) * scale;
}

// ---------------------------------------------------------------------------
extern "C" void kernel_launch(void* const* d_in, const int* in_sizes, int n_in,
                              void* d_out, int out_size, void* d_ws,
                              size_t ws_size, hipStream_t stream) {
  const float* x = (const float*)d_in[0];
  const int* edge_index = (const int*)d_in[1];
  const int* edge_type = (const int*)d_in[2];
  const float* W1 = (const float*)d_in[3];
  const float* q1 = (const float*)d_in[4];
  const float* k1 = (const float*)d_in[5];
  const float* b1 = (const float*)d_in[6];
  const float* Wmu = (const float*)d_in[7];
  const float* qmu = (const float*)d_in[8];
  const float* kmu = (const float*)d_in[9];
  const float* bmu = (const float*)d_in[10];
  const float* Wlv = (const float*)d_in[11];
  const float* qlv = (const float*)d_in[12];
  const float* klv = (const float*)d_in[13];
  const float* blv = (const float*)d_in[14];
  const float* Wm = (const float*)d_in[15];
  const float* bm = (const float*)d_in[16];
  const float* Wl = (const float*)d_in[17];
  const float* bl = (const float*)d_in[18];

  const int N = in_sizes[0] / 128;     // 50000
  const int E = in_sizes[2];           // 1.6M
  const int R = in_sizes[3] / (128 * 64);  // 8

  float* out_mu = (float*)d_out;
  float* out_ls = (float*)d_out + (size_t)N * ODIM;

  // workspace carve (256B aligned)
  char* wsp = (char*)d_ws;
  size_t off = 0;
  auto carve = [&](size_t bytes) {
    void* p = wsp + off;
    off += (bytes + 255) & ~(size_t)255;
    return p;
  };
  float* t = (float*)carve((size_t)R * N * HDIM * sizeof(float));   // 102.4 MB
  float* aq = (float*)carve((size_t)R * N * sizeof(float));
  float* ak = (float*)carve((size_t)R * N * sizeof(float));
  float* hidden = (float*)carve((size_t)N * HDIM * sizeof(float));
  float* fmu = (float*)carve((size_t)N * HDIM * sizeof(float));
  float* flv = (float*)carve((size_t)N * HDIM * sizeof(float));
  int* deg = (int*)carve((size_t)N * sizeof(int));
  int* fill = (int*)carve((size_t)N * sizeof(int));
  int* row_ptr = (int*)carve((size_t)(N + 1) * sizeof(int));
  int* edges = (int*)carve((size_t)E * sizeof(int));

  const int* e_src = edge_index;
  const int* e_dst = edge_index + E;

  // ---- CSR build (graph is identical across the 3 layers) ----
  hipMemsetAsync(deg, 0, (size_t)N * sizeof(int), stream);
  hipMemsetAsync(fill, 0, (size_t)N * sizeof(int), stream);
  count_deg_kernel<<<(E + 255) / 256, 256, 0, stream>>>(e_dst, deg, E);
  scan_kernel<<<1, 1024, 0, stream>>>(deg, row_ptr, N);
  scatter_kernel<<<(E + 255) / 256, 256, 0, stream>>>(e_src, e_dst, edge_type,
                                                      row_ptr, fill, edges, E);

  const int tiles = (N + 31) / 32;
  const int agg_blocks = (N + 3) / 4;  // 4 waves/block, 1 wave/node

  // ---- layer 1: IN=128 -> H=64 ----
  transform_kernel<128><<<dim3(tiles, R), 256, 0, stream>>>(x, W1, q1, k1, t,
                                                            aq, ak, N);
  aggregate_kernel<<<agg_blocks, 256, 0, stream>>>(row_ptr, edges, t, aq, ak,
                                                   b1, hidden, N);

  // ---- conv_mu: H -> H ----
  transform_kernel<64><<<dim3(tiles, R), 256, 0, stream>>>(hidden, Wmu, qmu,
                                                           kmu, t, aq, ak, N);
  aggregate_kernel<<<agg_blocks, 256, 0, stream>>>(row_ptr, edges, t, aq, ak,
                                                   bmu, fmu, N);

  // ---- conv_logvar: H -> H ----
  transform_kernel<64><<<dim3(tiles, R), 256, 0, stream>>>(hidden, Wlv, qlv,
                                                           klv, t, aq, ak, N);
  aggregate_kernel<<<agg_blocks, 256, 0, stream>>>(row_ptr, edges, t, aq, ak,
                                                   blv, flv, N);

  // ---- output linears: mu and logstd = 0.5*logvar ----
  const int lin_blocks = (N * ODIM + 255) / 256;
  linear_kernel<<<lin_blocks, 256, 0, stream>>>(fmu, Wm, bm, out_mu, 1.0f, N);
  linear_kernel<<<lin_blocks, 256, 0, stream>>>(flv, Wl, bl, out_ls, 0.5f, N);
}

// Round 2
// 805.328 us; speedup vs baseline: 1.7426x; 1.7426x over previous
//
#include <hip/hip_runtime.h>
#include <cstdint>

// N=50000 nodes, E=1.6M edges, IN=128, H=64, OUT=32, R=8
#define HDIM 64
#define ODIM 32
#define NEG_SLOPE 0.2f
#define SCHUNK 2048

// ---------------------------------------------------------------------------
// CSR build
// ---------------------------------------------------------------------------
__global__ __launch_bounds__(256) void count_deg_kernel(
    const int* __restrict__ dst, int* __restrict__ deg, int E) {
  int e = blockIdx.x * 256 + threadIdx.x;
  if (e < E) atomicAdd(&deg[dst[e]], 1);
}

// phase 1: per-chunk (2048) sums
__global__ __launch_bounds__(256) void scan_p1(const int* __restrict__ deg,
                                               int* __restrict__ bsum, int n) {
  int base = blockIdx.x * SCHUNK + threadIdx.x * 8;
  int s = 0;
#pragma unroll
  for (int j = 0; j < 8; j++) {
    int i = base + j;
    if (i < n) s += deg[i];
  }
#pragma unroll
  for (int d = 1; d < 64; d <<= 1) s += __shfl_xor(s, d, 64);
  __shared__ int ws[4];
  if ((threadIdx.x & 63) == 0) ws[threadIdx.x >> 6] = s;
  __syncthreads();
  if (threadIdx.x == 0) bsum[blockIdx.x] = ws[0] + ws[1] + ws[2] + ws[3];
}

// phase 2: exclusive scan of chunk sums (nb <= 64), launch 1 block x 64
__global__ void scan_p2(int* bsum, int nb) {
  int i = threadIdx.x;
  int v = (i < nb) ? bsum[i] : 0;
  int orig = v;
#pragma unroll
  for (int d = 1; d < 64; d <<= 1) {
    int up = __shfl_up(v, d, 64);
    if (i >= d) v += up;
  }
  if (i < nb) bsum[i] = v - orig;  // exclusive offset of chunk i
}

// phase 3: local inclusive scan + chunk offset -> row_ptr[1..n]
__global__ __launch_bounds__(256) void scan_p3(const int* __restrict__ deg,
                                               const int* __restrict__ bsum,
                                               int* __restrict__ row_ptr,
                                               int n) {
  int base = blockIdx.x * SCHUNK + threadIdx.x * 8;
  int vals[8];
  int s = 0;
#pragma unroll
  for (int j = 0; j < 8; j++) {
    int i = base + j;
    vals[j] = (i < n) ? deg[i] : 0;
    s += vals[j];
  }
  int lane = threadIdx.x & 63, w = threadIdx.x >> 6;
  int v = s;
#pragma unroll
  for (int d = 1; d < 64; d <<= 1) {
    int up = __shfl_up(v, d, 64);
    if (lane >= d) v += up;
  }
  __shared__ int wsum[4];
  if (lane == 63) wsum[w] = v;
  __syncthreads();
  int woff = 0;
#pragma unroll
  for (int i = 0; i < 4; i++) woff += (i < w) ? wsum[i] : 0;
  int off = bsum[blockIdx.x] + woff + v - s;  // exclusive prefix for thread
#pragma unroll
  for (int j = 0; j < 8; j++) {
    int i = base + j;
    off += vals[j];
    if (i < n) row_ptr[i + 1] = off;
  }
  if (blockIdx.x == 0 && threadIdx.x == 0) row_ptr[0] = 0;
}

// pack src (N=50000 < 65536 -> 16 bits) | etype<<16
__global__ __launch_bounds__(256) void scatter_kernel(
    const int* __restrict__ src, const int* __restrict__ dst,
    const int* __restrict__ etype, const int* __restrict__ row_ptr,
    int* __restrict__ fill, int* __restrict__ edges, int E) {
  int e = blockIdx.x * 256 + threadIdx.x;
  if (e < E) {
    int d = dst[e];
    int pos = row_ptr[d] + atomicAdd(&fill[d], 1);
    edges[pos] = src[e] | (etype[e] << 16);
  }
}

// ---------------------------------------------------------------------------
// Per-relation transform: t[r,n,:] = f[n,:] @ W[r]  (+ aq/ak epilogue)
// Register-tiled GEMM: block tile 256 nodes x 64 out, thread tile 8x8,
// K chunks of 32 staged transposed in LDS. Per k: 4 ds_read_b128 / 64 FMA.
// ---------------------------------------------------------------------------
template <int CIN>
__global__ __launch_bounds__(256) void transform_kernel(
    const float* __restrict__ f, const float* __restrict__ W,
    const float* __restrict__ q, const float* __restrict__ k,
    float* __restrict__ t, float* __restrict__ aq, float* __restrict__ ak,
    int N) {
  constexpr int KC = 32;
  constexpr int FLD = 260;  // Fl leading dim (floats), pad breaks 32-stride
  constexpr int WLD = 68;
  __shared__ float Fl[KC * FLD];  // [k][n]  33.3 KB
  __shared__ float Wl[KC * WLD];  // [k][o]   8.7 KB

  const int r = blockIdx.y;
  const int n0 = blockIdx.x * 256;
  const int tid = threadIdx.x;
  const int nt = tid >> 3;  // 0..31 node group
  const int ot = tid & 7;   // 0..7 output group
  const int on0 = ot * 8;

  float acc[8][8];
#pragma unroll
  for (int i = 0; i < 8; i++)
#pragma unroll
    for (int j = 0; j < 8; j++) acc[i][j] = 0.f;

  for (int k0 = 0; k0 < CIN; k0 += KC) {
    // stage F transposed: thread reads f[n][k0+kk .. +3] (coalesced float4)
    {
      const int kk = (tid & 7) * 4;
      const int nb = tid >> 3;
#pragma unroll
      for (int i = 0; i < 8; i++) {
        const int n = nb + i * 32;
        const int gn = n0 + n;
        float4 v = make_float4(0.f, 0.f, 0.f, 0.f);
        if (gn < N) v = *(const float4*)&f[(size_t)gn * CIN + k0 + kk];
        Fl[(kk + 0) * FLD + n] = v.x;
        Fl[(kk + 1) * FLD + n] = v.y;
        Fl[(kk + 2) * FLD + n] = v.z;
        Fl[(kk + 3) * FLD + n] = v.w;
      }
    }
    // stage W: thread reads W[r][k0+kr][oc..oc+3] (coalesced float4)
    {
      const int oc = (tid & 15) * 4;
#pragma unroll
      for (int i = 0; i < 2; i++) {
        const int kr = (tid >> 4) + i * 16;
        float4 v = *(const float4*)&W[((size_t)r * CIN + k0 + kr) * 64 + oc];
        *(float4*)&Wl[kr * WLD + oc] = v;
      }
    }
    __syncthreads();

#pragma unroll 4
    for (int kk = 0; kk < KC; kk++) {
      float4 fA = *(const float4*)&Fl[kk * FLD + nt * 8];
      float4 fB = *(const float4*)&Fl[kk * FLD + nt * 8 + 4];
      float4 wA = *(const float4*)&Wl[kk * WLD + on0];
      float4 wB = *(const float4*)&Wl[kk * WLD + on0 + 4];
      float fv[8] = {fA.x, fA.y, fA.z, fA.w, fB.x, fB.y, fB.z, fB.w};
      float wv[8] = {wA.x, wA.y, wA.z, wA.w, wB.x, wB.y, wB.z, wB.w};
#pragma unroll
      for (int i = 0; i < 8; i++)
#pragma unroll
        for (int j = 0; j < 8; j++) acc[i][j] = fmaf(fv[i], wv[j], acc[i][j]);
    }
    __syncthreads();
  }

  float qv[8], kv[8];
#pragma unroll
  for (int j = 0; j < 8; j++) {
    qv[j] = q[on0 + j];
    kv[j] = k[on0 + j];
  }

#pragma unroll
  for (int i = 0; i < 8; i++) {
    const int gn = n0 + nt * 8 + i;
    const bool valid = gn < N;
    if (valid) {
      float* dst = &t[((size_t)r * N + gn) * 64 + on0];
      *(float4*)dst = make_float4(acc[i][0], acc[i][1], acc[i][2], acc[i][3]);
      *(float4*)(dst + 4) =
          make_float4(acc[i][4], acc[i][5], acc[i][6], acc[i][7]);
    }
    float vq = 0.f, vk = 0.f;
#pragma unroll
    for (int j = 0; j < 8; j++) {
      vq = fmaf(acc[i][j], qv[j], vq);
      vk = fmaf(acc[i][j], kv[j], vk);
    }
#pragma unroll
    for (int d = 1; d < 8; d <<= 1) {
      vq += __shfl_xor(vq, d, 64);
      vk += __shfl_xor(vk, d, 64);
    }
    if (ot == 0 && valid) {
      aq[(size_t)r * N + gn] = vq;
      ak[(size_t)r * N + gn] = vk;
    }
  }
}

// ---------------------------------------------------------------------------
// Aggregate: one wave per destination node, online softmax, 4-edge batching
// for memory-level parallelism. lane = output channel.
// ---------------------------------------------------------------------------
__global__ __launch_bounds__(256) void aggregate_kernel(
    const int* __restrict__ row_ptr, const int* __restrict__ edges,
    const float* __restrict__ t, const float* __restrict__ aq,
    const float* __restrict__ ak, const float* __restrict__ bias,
    float* __restrict__ out, int N) {
  const int wid = (blockIdx.x * 256 + threadIdx.x) >> 6;  // node id
  const int o = threadIdx.x & 63;
  if (wid >= N) return;
  const int beg = row_ptr[wid];
  const int end = row_ptr[wid + 1];

  // per-node aq[r,wid] preloaded into lanes 0..7, fetched via shuffle
  const float aqw = (o < 8) ? aq[(size_t)o * N + wid] : 0.f;

  float m = -1e30f, s = 0.f, acc = 0.f;
  for (int e = beg; e < end; e += 4) {
    float tv[4], av[4];
#pragma unroll
    for (int j = 0; j < 4; j++) {
      const bool valid = (e + j) < end;
      const int packed = edges[valid ? (e + j) : beg];
      const int src = packed & 0xFFFF;
      const int rr = packed >> 16;
      tv[j] = t[((size_t)rr * N + src) * 64 + o];  // coalesced 256B gather
      float a = __shfl(aqw, rr, 64) + ak[(size_t)rr * N + src];
      a = (a >= 0.f) ? a : NEG_SLOPE * a;
      av[j] = valid ? a : -1e30f;  // exp(-1e30 - nm) == 0
    }
#pragma unroll
    for (int j = 0; j < 4; j++) {
      const float nm = fmaxf(m, av[j]);
      const float scale = __expf(m - nm);
      const float p = __expf(av[j] - nm);
      s = s * scale + p;
      acc = acc * scale + p * tv[j];
      m = nm;
    }
  }
  const float res = acc / (s + 1e-16f) + bias[o];
  out[(size_t)wid * 64 + o] = fmaxf(res, 0.f);  // relu
}

// ---------------------------------------------------------------------------
// Final linear: out[n,:ODIM] = (f[n,:64] @ W + b) * scale
// ---------------------------------------------------------------------------
__global__ __launch_bounds__(256) void linear_kernel(
    const float* __restrict__ f, const float* __restrict__ W,
    const float* __restrict__ b, float* __restrict__ out, float scale, int N) {
  __shared__ float Wl[HDIM * ODIM];
  __shared__ float bl[ODIM];
  for (int i = threadIdx.x; i < HDIM * ODIM; i += 256) Wl[i] = W[i];
  if (threadIdx.x < ODIM) bl[threadIdx.x] = b[threadIdx.x];
  __syncthreads();
  const int tid = blockIdx.x * 256 + threadIdx.x;
  const int n = tid >> 5;
  const int o = tid & 31;
  if (n >= N) return;
  const float* fr = f + (size_t)n * HDIM;
  float acc = 0.f;
#pragma unroll
  for (int i = 0; i < HDIM; i++) acc = fmaf(fr[i], Wl[i * ODIM + o], acc);
  out[(size_t)n * ODIM + o] = (acc + bl[o]) * scale;
}

// ---------------------------------------------------------------------------
extern "C" void kernel_launch(void* const* d_in, const int* in_sizes, int n_in,
                              void* d_out, int out_size, void* d_ws,
                              size_t ws_size, hipStream_t stream) {
  const float* x = (const float*)d_in[0];
  const int* edge_index = (const int*)d_in[1];
  const int* edge_type = (const int*)d_in[2];
  const float* W1 = (const float*)d_in[3];
  const float* q1 = (const float*)d_in[4];
  const float* k1 = (const float*)d_in[5];
  const float* b1 = (const float*)d_in[6];
  const float* Wmu = (const float*)d_in[7];
  const float* qmu = (const float*)d_in[8];
  const float* kmu = (const float*)d_in[9];
  const float* bmu = (const float*)d_in[10];
  const float* Wlv = (const float*)d_in[11];
  const float* qlv = (const float*)d_in[12];
  const float* klv = (const float*)d_in[13];
  const float* blv = (const float*)d_in[14];
  const float* Wm = (const float*)d_in[15];
  const float* bm = (const float*)d_in[16];
  const float* Wl = (const float*)d_in[17];
  const float* bl = (const float*)d_in[18];

  const int N = in_sizes[0] / 128;         // 50000
  const int E = in_sizes[2];               // 1.6M
  const int R = in_sizes[3] / (128 * 64);  // 8

  float* out_mu = (float*)d_out;
  float* out_ls = (float*)d_out + (size_t)N * ODIM;

  char* wsp = (char*)d_ws;
  size_t off = 0;
  auto carve = [&](size_t bytes) {
    void* p = wsp + off;
    off += (bytes + 255) & ~(size_t)255;
    return p;
  };
  float* t = (float*)carve((size_t)R * N * HDIM * sizeof(float));  // 102.4 MB
  float* aq = (float*)carve((size_t)R * N * sizeof(float));
  float* ak = (float*)carve((size_t)R * N * sizeof(float));
  float* hidden = (float*)carve((size_t)N * HDIM * sizeof(float));
  float* fmu = (float*)carve((size_t)N * HDIM * sizeof(float));
  float* flv = (float*)carve((size_t)N * HDIM * sizeof(float));
  int* deg = (int*)carve((size_t)N * sizeof(int));
  int* fill = (int*)carve((size_t)N * sizeof(int));
  int* row_ptr = (int*)carve((size_t)(N + 1) * sizeof(int));
  int* bsum = (int*)carve(256 * sizeof(int));
  int* edges = (int*)carve((size_t)E * sizeof(int));

  const int* e_src = edge_index;
  const int* e_dst = edge_index + E;

  // ---- CSR build ----
  hipMemsetAsync(deg, 0, (size_t)N * sizeof(int), stream);
  hipMemsetAsync(fill, 0, (size_t)N * sizeof(int), stream);
  count_deg_kernel<<<(E + 255) / 256, 256, 0, stream>>>(e_dst, deg, E);
  const int nchunk = (N + SCHUNK - 1) / SCHUNK;  // 25 <= 64
  scan_p1<<<nchunk, 256, 0, stream>>>(deg, bsum, N);
  scan_p2<<<1, 64, 0, stream>>>(bsum, nchunk);
  scan_p3<<<nchunk, 256, 0, stream>>>(deg, bsum, row_ptr, N);
  scatter_kernel<<<(E + 255) / 256, 256, 0, stream>>>(e_src, e_dst, edge_type,
                                                      row_ptr, fill, edges, E);

  const int tiles = (N + 255) / 256;
  const int agg_blocks = (N + 3) / 4;  // 1 wave/node

  // ---- layer 1: IN=128 -> H=64 ----
  transform_kernel<128><<<dim3(tiles, R), 256, 0, stream>>>(x, W1, q1, k1, t,
                                                            aq, ak, N);
  aggregate_kernel<<<agg_blocks, 256, 0, stream>>>(row_ptr, edges, t, aq, ak,
                                                   b1, hidden, N);

  // ---- conv_mu: H -> H ----
  transform_kernel<64><<<dim3(tiles, R), 256, 0, stream>>>(hidden, Wmu, qmu,
                                                           kmu, t, aq, ak, N);
  aggregate_kernel<<<agg_blocks, 256, 0, stream>>>(row_ptr, edges, t, aq, ak,
                                                   bmu, fmu, N);

  // ---- conv_logvar: H -> H ----
  transform_kernel<64><<<dim3(tiles, R), 256, 0, stream>>>(hidden, Wlv, qlv,
                                                           klv, t, aq, ak, N);
  aggregate_kernel<<<agg_blocks, 256, 0, stream>>>(row_ptr, edges, t, aq, ak,
                                                   blv, flv, N);

  // ---- output linears ----
  const int lin_blocks = (N * ODIM + 255) / 256;
  linear_kernel<<<lin_blocks, 256, 0, stream>>>(fmu, Wm, bm, out_mu, 1.0f, N);
  linear_kernel<<<lin_blocks, 256, 0, stream>>>(flv, Wl, bl, out_ls, 0.5f, N);
}

// Round 3
// 741.756 us; speedup vs baseline: 1.8919x; 1.0857x over previous
//
#include <hip/hip_runtime.h>
#include <cstdint>

// N=50000 nodes, E=1.6M edges, IN=128, H=64, OUT=32, R=8
#define HDIM 64
#define ODIM 32
#define NEG_SLOPE 0.2f
#define SCHUNK 2048

// ---------------------------------------------------------------------------
// CSR build
// ---------------------------------------------------------------------------
__global__ __launch_bounds__(256) void count_deg_kernel(
    const int* __restrict__ dst, int* __restrict__ deg, int E) {
  int e = blockIdx.x * 256 + threadIdx.x;
  if (e < E) atomicAdd(&deg[dst[e]], 1);
}

__global__ __launch_bounds__(256) void scan_p1(const int* __restrict__ deg,
                                               int* __restrict__ bsum, int n) {
  int base = blockIdx.x * SCHUNK + threadIdx.x * 8;
  int s = 0;
#pragma unroll
  for (int j = 0; j < 8; j++) {
    int i = base + j;
    if (i < n) s += deg[i];
  }
#pragma unroll
  for (int d = 1; d < 64; d <<= 1) s += __shfl_xor(s, d, 64);
  __shared__ int ws[4];
  if ((threadIdx.x & 63) == 0) ws[threadIdx.x >> 6] = s;
  __syncthreads();
  if (threadIdx.x == 0) bsum[blockIdx.x] = ws[0] + ws[1] + ws[2] + ws[3];
}

__global__ void scan_p2(int* bsum, int nb) {
  int i = threadIdx.x;
  int v = (i < nb) ? bsum[i] : 0;
  int orig = v;
#pragma unroll
  for (int d = 1; d < 64; d <<= 1) {
    int up = __shfl_up(v, d, 64);
    if (i >= d) v += up;
  }
  if (i < nb) bsum[i] = v - orig;
}

__global__ __launch_bounds__(256) void scan_p3(const int* __restrict__ deg,
                                               const int* __restrict__ bsum,
                                               int* __restrict__ row_ptr,
                                               int n) {
  int base = blockIdx.x * SCHUNK + threadIdx.x * 8;
  int vals[8];
  int s = 0;
#pragma unroll
  for (int j = 0; j < 8; j++) {
    int i = base + j;
    vals[j] = (i < n) ? deg[i] : 0;
    s += vals[j];
  }
  int lane = threadIdx.x & 63, w = threadIdx.x >> 6;
  int v = s;
#pragma unroll
  for (int d = 1; d < 64; d <<= 1) {
    int up = __shfl_up(v, d, 64);
    if (lane >= d) v += up;
  }
  __shared__ int wsum[4];
  if (lane == 63) wsum[w] = v;
  __syncthreads();
  int woff = 0;
#pragma unroll
  for (int i = 0; i < 4; i++) woff += (i < w) ? wsum[i] : 0;
  int off = bsum[blockIdx.x] + woff + v - s;
#pragma unroll
  for (int j = 0; j < 8; j++) {
    int i = base + j;
    off += vals[j];
    if (i < n) row_ptr[i + 1] = off;
  }
  if (blockIdx.x == 0 && threadIdx.x == 0) row_ptr[0] = 0;
}

__global__ __launch_bounds__(256) void scatter_kernel(
    const int* __restrict__ src, const int* __restrict__ dst,
    const int* __restrict__ etype, const int* __restrict__ row_ptr,
    int* __restrict__ fill, int* __restrict__ edges, int E) {
  int e = blockIdx.x * 256 + threadIdx.x;
  if (e < E) {
    int d = dst[e];
    int pos = row_ptr[d] + atomicAdd(&fill[d], 1);
    edges[pos] = src[e] | (etype[e] << 16);  // N < 65536
  }
}

// ---------------------------------------------------------------------------
// Single transform (layer 1, and fallback): t[r,n,:] = f[n,:] @ W[r]
// grid (R, tiles): r fast -> 8 co-resident blocks share one F tile in L2.
// ---------------------------------------------------------------------------
template <int CIN>
__global__ __launch_bounds__(256) void transform_kernel(
    const float* __restrict__ f, const float* __restrict__ W,
    const float* __restrict__ q, const float* __restrict__ k,
    float* __restrict__ t, float* __restrict__ aq, float* __restrict__ ak,
    int N) {
  constexpr int KC = 32;
  constexpr int FLD = 260;
  constexpr int WLD = 68;
  __shared__ float Fl[KC * FLD];
  __shared__ float Wl[KC * WLD];

  const int r = blockIdx.x;
  const int n0 = blockIdx.y * 256;
  const int tid = threadIdx.x;
  const int nt = tid >> 3;
  const int ot = tid & 7;
  const int on0 = ot * 8;

  float acc[8][8];
#pragma unroll
  for (int i = 0; i < 8; i++)
#pragma unroll
    for (int j = 0; j < 8; j++) acc[i][j] = 0.f;

  for (int k0 = 0; k0 < CIN; k0 += KC) {
    {
      const int kk = (tid & 7) * 4;
      const int nb = tid >> 3;
#pragma unroll
      for (int i = 0; i < 8; i++) {
        const int n = nb + i * 32;
        const int gn = n0 + n;
        float4 v = make_float4(0.f, 0.f, 0.f, 0.f);
        if (gn < N) v = *(const float4*)&f[(size_t)gn * CIN + k0 + kk];
        Fl[(kk + 0) * FLD + n] = v.x;
        Fl[(kk + 1) * FLD + n] = v.y;
        Fl[(kk + 2) * FLD + n] = v.z;
        Fl[(kk + 3) * FLD + n] = v.w;
      }
    }
    {
      const int oc = (tid & 15) * 4;
#pragma unroll
      for (int i = 0; i < 2; i++) {
        const int kr = (tid >> 4) + i * 16;
        float4 v = *(const float4*)&W[((size_t)r * CIN + k0 + kr) * 64 + oc];
        *(float4*)&Wl[kr * WLD + oc] = v;
      }
    }
    __syncthreads();

#pragma unroll 4
    for (int kk = 0; kk < KC; kk++) {
      float4 fA = *(const float4*)&Fl[kk * FLD + nt * 8];
      float4 fB = *(const float4*)&Fl[kk * FLD + nt * 8 + 4];
      float4 wA = *(const float4*)&Wl[kk * WLD + on0];
      float4 wB = *(const float4*)&Wl[kk * WLD + on0 + 4];
      float fv[8] = {fA.x, fA.y, fA.z, fA.w, fB.x, fB.y, fB.z, fB.w};
      float wv[8] = {wA.x, wA.y, wA.z, wA.w, wB.x, wB.y, wB.z, wB.w};
#pragma unroll
      for (int i = 0; i < 8; i++)
#pragma unroll
        for (int j = 0; j < 8; j++) acc[i][j] = fmaf(fv[i], wv[j], acc[i][j]);
    }
    __syncthreads();
  }

  float qv[8], kv[8];
#pragma unroll
  for (int j = 0; j < 8; j++) {
    qv[j] = q[on0 + j];
    kv[j] = k[on0 + j];
  }

#pragma unroll
  for (int i = 0; i < 8; i++) {
    const int gn = n0 + nt * 8 + i;
    const bool valid = gn < N;
    if (valid) {
      float* dst = &t[((size_t)r * N + gn) * 64 + on0];
      *(float4*)dst = make_float4(acc[i][0], acc[i][1], acc[i][2], acc[i][3]);
      *(float4*)(dst + 4) =
          make_float4(acc[i][4], acc[i][5], acc[i][6], acc[i][7]);
    }
    float vq = 0.f, vk = 0.f;
#pragma unroll
    for (int j = 0; j < 8; j++) {
      vq = fmaf(acc[i][j], qv[j], vq);
      vk = fmaf(acc[i][j], kv[j], vk);
    }
#pragma unroll
    for (int d = 1; d < 8; d <<= 1) {
      vq += __shfl_xor(vq, d, 64);
      vk += __shfl_xor(vk, d, 64);
    }
    if (ot == 0 && valid) {
      aq[(size_t)r * N + gn] = vq;
      ak[(size_t)r * N + gn] = vk;
    }
  }
}

// ---------------------------------------------------------------------------
// Fused mu+lv transform (CIN=64): stage F once, compute both relations' W.
// t2: [R][N][2][64] interleaved; aq2/ak2: [(mat*8+r)][N].
// Block: 128-node tile, thread tile 8n x 8o x 1mat (ot&8 selects mat).
// ---------------------------------------------------------------------------
__global__ __launch_bounds__(256) void transform2_kernel(
    const float* __restrict__ f, const float* __restrict__ Wa,
    const float* __restrict__ Wb, const float* __restrict__ qa,
    const float* __restrict__ ka, const float* __restrict__ qb,
    const float* __restrict__ kb, float* __restrict__ t2,
    float* __restrict__ aq2, float* __restrict__ ak2, int N) {
  constexpr int CIN = 64, KC = 32;
  constexpr int FLD = 132;  // 128 + 4 pad
  constexpr int WLD = 68;
  __shared__ float Fl[KC * FLD];
  __shared__ float Wl[2][KC * WLD + 4];  // +4: offsets mat1 banks by 4

  const int r = blockIdx.x;
  const int n0 = blockIdx.y * 128;
  const int tid = threadIdx.x;
  const int nt = tid >> 4;       // 0..15
  const int ot = tid & 15;       // 0..15
  const int mat = ot >> 3;       // 0=mu, 1=lv
  const int on0 = (ot & 7) * 8;  // 0..56

  float acc[8][8];
#pragma unroll
  for (int i = 0; i < 8; i++)
#pragma unroll
    for (int j = 0; j < 8; j++) acc[i][j] = 0.f;

  for (int k0 = 0; k0 < CIN; k0 += KC) {
    {
      const int kk = (tid & 7) * 4;
      const int nb = tid >> 3;  // 0..31
#pragma unroll
      for (int i = 0; i < 4; i++) {
        const int n = nb + i * 32;
        const int gn = n0 + n;
        float4 v = make_float4(0.f, 0.f, 0.f, 0.f);
        if (gn < N) v = *(const float4*)&f[(size_t)gn * CIN + k0 + kk];
        Fl[(kk + 0) * FLD + n] = v.x;
        Fl[(kk + 1) * FLD + n] = v.y;
        Fl[(kk + 2) * FLD + n] = v.z;
        Fl[(kk + 3) * FLD + n] = v.w;
      }
    }
    {
      const int oc = (tid & 15) * 4;
#pragma unroll
      for (int i = 0; i < 2; i++) {
        const int kr = (tid >> 4) + i * 16;
        float4 va = *(const float4*)&Wa[((size_t)r * CIN + k0 + kr) * 64 + oc];
        float4 vb = *(const float4*)&Wb[((size_t)r * CIN + k0 + kr) * 64 + oc];
        *(float4*)&Wl[0][kr * WLD + oc] = va;
        *(float4*)&Wl[1][kr * WLD + oc] = vb;
      }
    }
    __syncthreads();

#pragma unroll 4
    for (int kk = 0; kk < KC; kk++) {
      float4 fA = *(const float4*)&Fl[kk * FLD + nt * 8];
      float4 fB = *(const float4*)&Fl[kk * FLD + nt * 8 + 4];
      float4 wA = *(const float4*)&Wl[mat][kk * WLD + on0];
      float4 wB = *(const float4*)&Wl[mat][kk * WLD + on0 + 4];
      float fv[8] = {fA.x, fA.y, fA.z, fA.w, fB.x, fB.y, fB.z, fB.w};
      float wv[8] = {wA.x, wA.y, wA.z, wA.w, wB.x, wB.y, wB.z, wB.w};
#pragma unroll
      for (int i = 0; i < 8; i++)
#pragma unroll
        for (int j = 0; j < 8; j++) acc[i][j] = fmaf(fv[i], wv[j], acc[i][j]);
    }
    __syncthreads();
  }

  const float* qsel = mat ? qb : qa;
  const float* ksel = mat ? kb : ka;
  float qv[8], kv[8];
#pragma unroll
  for (int j = 0; j < 8; j++) {
    qv[j] = qsel[on0 + j];
    kv[j] = ksel[on0 + j];
  }

#pragma unroll
  for (int i = 0; i < 8; i++) {
    const int gn = n0 + nt * 8 + i;
    const bool valid = gn < N;
    if (valid) {
      float* dst = &t2[((size_t)r * N + gn) * 128 + mat * 64 + on0];
      *(float4*)dst = make_float4(acc[i][0], acc[i][1], acc[i][2], acc[i][3]);
      *(float4*)(dst + 4) =
          make_float4(acc[i][4], acc[i][5], acc[i][6], acc[i][7]);
    }
    float vq = 0.f, vk = 0.f;
#pragma unroll
    for (int j = 0; j < 8; j++) {
      vq = fmaf(acc[i][j], qv[j], vq);
      vk = fmaf(acc[i][j], kv[j], vk);
    }
#pragma unroll
    for (int d = 1; d < 8; d <<= 1) {  // reduce over ot&7 (lane bits 0-2)
      vq += __shfl_xor(vq, d, 64);
      vk += __shfl_xor(vk, d, 64);
    }
    if ((ot & 7) == 0 && valid) {
      aq2[(size_t)(mat * 8 + r) * N + gn] = vq;
      ak2[(size_t)(mat * 8 + r) * N + gn] = vk;
    }
  }
}

// ---------------------------------------------------------------------------
// Single aggregate (layer 1 + fallback): one wave per dst node, online softmax
// ---------------------------------------------------------------------------
__global__ __launch_bounds__(256) void aggregate_kernel(
    const int* __restrict__ row_ptr, const int* __restrict__ edges,
    const float* __restrict__ t, const float* __restrict__ aq,
    const float* __restrict__ ak, const float* __restrict__ bias,
    float* __restrict__ out, int N) {
  const int wid = (blockIdx.x * 256 + threadIdx.x) >> 6;
  const int o = threadIdx.x & 63;
  if (wid >= N) return;
  const int beg = row_ptr[wid];
  const int end = row_ptr[wid + 1];

  const float aqw = (o < 8) ? aq[(size_t)o * N + wid] : 0.f;

  float m = -1e30f, s = 0.f, acc = 0.f;
  for (int e = beg; e < end; e += 4) {
    float tv[4], av[4];
#pragma unroll
    for (int j = 0; j < 4; j++) {
      const bool valid = (e + j) < end;
      const int packed = edges[valid ? (e + j) : beg];
      const int src = packed & 0xFFFF;
      const int rr = packed >> 16;
      tv[j] = t[((size_t)rr * N + src) * 64 + o];
      float a = __shfl(aqw, rr, 64) + ak[(size_t)rr * N + src];
      a = (a >= 0.f) ? a : NEG_SLOPE * a;
      av[j] = valid ? a : -1e30f;
    }
#pragma unroll
    for (int j = 0; j < 4; j++) {
      const float nm = fmaxf(m, av[j]);
      const float scale = __expf(m - nm);
      const float p = __expf(av[j] - nm);
      s = s * scale + p;
      acc = acc * scale + p * tv[j];
      m = nm;
    }
  }
  const float res = acc / (s + 1e-16f) + bias[o];
  out[(size_t)wid * 64 + o] = fmaxf(res, 0.f);
}

// ---------------------------------------------------------------------------
// Fused mu+lv aggregate + final linears. One wave per node; both t2 halves
// per edge; epilogue computes h@Wm / h@Wl via LDS and writes d_out directly.
// ---------------------------------------------------------------------------
__global__ __launch_bounds__(256) void aggregate2_kernel(
    const int* __restrict__ row_ptr, const int* __restrict__ edges,
    const float* __restrict__ t2, const float* __restrict__ aq2,
    const float* __restrict__ ak2, const float* __restrict__ bmu,
    const float* __restrict__ blv, const float* __restrict__ Wm,
    const float* __restrict__ bm, const float* __restrict__ Wlin,
    const float* __restrict__ bl, float* __restrict__ out_mu,
    float* __restrict__ out_ls, int N) {
  __shared__ float WmL[2048];
  __shared__ float WlL[2048];
  __shared__ float bL[64];
  __shared__ float hL[4][130];
  const int tid = threadIdx.x;
  for (int i = tid; i < 2048; i += 256) {
    WmL[i] = Wm[i];
    WlL[i] = Wlin[i];
  }
  if (tid < 32) {
    bL[tid] = bm[tid];
    bL[32 + tid] = bl[tid];
  }
  __syncthreads();

  const int w = tid >> 6;
  const int o = tid & 63;
  int wid = blockIdx.x * 4 + w;
  const bool valid = wid < N;
  if (!valid) wid = N - 1;
  const int beg = row_ptr[wid];
  const int end = valid ? row_ptr[wid + 1] : beg;

  const float aqw = (o < 16) ? aq2[(size_t)o * N + wid] : 0.f;

  float m0 = -1e30f, s0 = 0.f, c0 = 0.f;
  float m1 = -1e30f, s1 = 0.f, c1 = 0.f;
  for (int e = beg; e < end; e += 4) {
    float tv0[4], tv1[4], a0[4], a1[4];
#pragma unroll
    for (int j = 0; j < 4; j++) {
      const bool v = (e + j) < end;
      const int packed = edges[v ? (e + j) : beg];
      const int src = packed & 0xFFFF;
      const int rr = packed >> 16;
      const size_t base = ((size_t)rr * N + src) * 128;
      tv0[j] = t2[base + o];
      tv1[j] = t2[base + 64 + o];
      float aa0 = __shfl(aqw, rr, 64) + ak2[(size_t)rr * N + src];
      float aa1 = __shfl(aqw, 8 + rr, 64) + ak2[(size_t)(8 + rr) * N + src];
      aa0 = (aa0 >= 0.f) ? aa0 : NEG_SLOPE * aa0;
      aa1 = (aa1 >= 0.f) ? aa1 : NEG_SLOPE * aa1;
      a0[j] = v ? aa0 : -1e30f;
      a1[j] = v ? aa1 : -1e30f;
    }
#pragma unroll
    for (int j = 0; j < 4; j++) {
      float nm = fmaxf(m0, a0[j]);
      float sc = __expf(m0 - nm);
      float p = __expf(a0[j] - nm);
      s0 = s0 * sc + p;
      c0 = c0 * sc + p * tv0[j];
      m0 = nm;
      nm = fmaxf(m1, a1[j]);
      sc = __expf(m1 - nm);
      p = __expf(a1[j] - nm);
      s1 = s1 * sc + p;
      c1 = c1 * sc + p * tv1[j];
      m1 = nm;
    }
  }
  const float h0 = fmaxf(c0 / (s0 + 1e-16f) + bmu[o], 0.f);
  const float h1 = fmaxf(c1 / (s1 + 1e-16f) + blv[o], 0.f);
  hL[w][o] = h0;
  hL[w][64 + o] = h1;
  __syncthreads();

  // lanes 0-31: mu linear; lanes 32-63: lv linear (0.5x for logstd)
  const float* hrow = &hL[w][(o >= 32) ? 64 : 0];
  const float* WL = (o >= 32) ? WlL : WmL;
  const int j = o & 31;
  float acc = 0.f;
#pragma unroll 8
  for (int c = 0; c < 64; c++) acc = fmaf(hrow[c], WL[c * 32 + j], acc);
  if (valid) {
    if (o < 32)
      out_mu[(size_t)wid * 32 + j] = acc + bL[j];
    else
      out_ls[(size_t)wid * 32 + j] = (acc + bL[32 + j]) * 0.5f;
  }
}

// ---------------------------------------------------------------------------
// Fallback final linear
// ---------------------------------------------------------------------------
__global__ __launch_bounds__(256) void linear_kernel(
    const float* __restrict__ f, const float* __restrict__ W,
    const float* __restrict__ b, float* __restrict__ out, float scale, int N) {
  __shared__ float Wl[HDIM * ODIM];
  __shared__ float bl[ODIM];
  for (int i = threadIdx.x; i < HDIM * ODIM; i += 256) Wl[i] = W[i];
  if (threadIdx.x < ODIM) bl[threadIdx.x] = b[threadIdx.x];
  __syncthreads();
  const int tid = blockIdx.x * 256 + threadIdx.x;
  const int n = tid >> 5;
  const int o = tid & 31;
  if (n >= N) return;
  const float* fr = f + (size_t)n * HDIM;
  float acc = 0.f;
#pragma unroll
  for (int i = 0; i < HDIM; i++) acc = fmaf(fr[i], Wl[i * ODIM + o], acc);
  out[(size_t)n * ODIM + o] = (acc + bl[o]) * scale;
}

// ---------------------------------------------------------------------------
extern "C" void kernel_launch(void* const* d_in, const int* in_sizes, int n_in,
                              void* d_out, int out_size, void* d_ws,
                              size_t ws_size, hipStream_t stream) {
  const float* x = (const float*)d_in[0];
  const int* edge_index = (const int*)d_in[1];
  const int* edge_type = (const int*)d_in[2];
  const float* W1 = (const float*)d_in[3];
  const float* q1 = (const float*)d_in[4];
  const float* k1 = (const float*)d_in[5];
  const float* b1 = (const float*)d_in[6];
  const float* Wmu = (const float*)d_in[7];
  const float* qmu = (const float*)d_in[8];
  const float* kmu = (const float*)d_in[9];
  const float* bmu = (const float*)d_in[10];
  const float* Wlv = (const float*)d_in[11];
  const float* qlv = (const float*)d_in[12];
  const float* klv = (const float*)d_in[13];
  const float* blv = (const float*)d_in[14];
  const float* Wm = (const float*)d_in[15];
  const float* bm = (const float*)d_in[16];
  const float* Wl = (const float*)d_in[17];
  const float* bl = (const float*)d_in[18];

  const int N = in_sizes[0] / 128;         // 50000
  const int E = in_sizes[2];               // 1.6M
  const int R = in_sizes[3] / (128 * 64);  // 8

  float* out_mu = (float*)d_out;
  float* out_ls = (float*)d_out + (size_t)N * ODIM;

  char* wsp = (char*)d_ws;
  size_t off = 0;
  auto carve = [&](size_t bytes) {
    void* p = wsp + off;
    off += (bytes + 255) & ~(size_t)255;
    return p;
  };

  const size_t t2_bytes = (size_t)R * N * 128 * sizeof(float);  // 204.8 MB
  const size_t fused_need = t2_bytes + 2 * (size_t)2 * R * N * sizeof(float) +
                            (size_t)N * HDIM * sizeof(float) +
                            3 * (size_t)(N + 1) * sizeof(int) + 2048 +
                            (size_t)E * sizeof(int) + 4096;
  const bool fused = ws_size >= fused_need;

  float *t2, *aq2, *ak2, *hidden, *fmu = nullptr, *flv = nullptr;
  if (fused) {
    t2 = (float*)carve(t2_bytes);
    aq2 = (float*)carve((size_t)2 * R * N * sizeof(float));
    ak2 = (float*)carve((size_t)2 * R * N * sizeof(float));
    hidden = (float*)carve((size_t)N * HDIM * sizeof(float));
  } else {
    t2 = (float*)carve((size_t)R * N * HDIM * sizeof(float));  // single t
    aq2 = (float*)carve((size_t)R * N * sizeof(float));
    ak2 = (float*)carve((size_t)R * N * sizeof(float));
    hidden = (float*)carve((size_t)N * HDIM * sizeof(float));
    fmu = (float*)carve((size_t)N * HDIM * sizeof(float));
    flv = (float*)carve((size_t)N * HDIM * sizeof(float));
  }
  int* deg = (int*)carve((size_t)N * sizeof(int));
  int* fill = (int*)carve((size_t)N * sizeof(int));
  int* row_ptr = (int*)carve((size_t)(N + 1) * sizeof(int));
  int* bsum = (int*)carve(256 * sizeof(int));
  int* edges = (int*)carve((size_t)E * sizeof(int));

  const int* e_src = edge_index;
  const int* e_dst = edge_index + E;

  // ---- CSR build ----
  hipMemsetAsync(deg, 0, (size_t)N * sizeof(int), stream);
  hipMemsetAsync(fill, 0, (size_t)N * sizeof(int), stream);
  count_deg_kernel<<<(E + 255) / 256, 256, 0, stream>>>(e_dst, deg, E);
  const int nchunk = (N + SCHUNK - 1) / SCHUNK;
  scan_p1<<<nchunk, 256, 0, stream>>>(deg, bsum, N);
  scan_p2<<<1, 64, 0, stream>>>(bsum, nchunk);
  scan_p3<<<nchunk, 256, 0, stream>>>(deg, bsum, row_ptr, N);
  scatter_kernel<<<(E + 255) / 256, 256, 0, stream>>>(e_src, e_dst, edge_type,
                                                      row_ptr, fill, edges, E);

  const int tiles256 = (N + 255) / 256;
  const int agg_blocks = (N + 3) / 4;

  // ---- layer 1: IN=128 -> H=64 (t2 buffer reused as [R][N][64]) ----
  transform_kernel<128><<<dim3(R, tiles256), 256, 0, stream>>>(
      x, W1, q1, k1, t2, aq2, ak2, N);
  aggregate_kernel<<<agg_blocks, 256, 0, stream>>>(row_ptr, edges, t2, aq2,
                                                   ak2, b1, hidden, N);

  if (fused) {
    // ---- fused conv_mu + conv_logvar ----
    const int tiles128 = (N + 127) / 128;
    transform2_kernel<<<dim3(R, tiles128), 256, 0, stream>>>(
        hidden, Wmu, Wlv, qmu, kmu, qlv, klv, t2, aq2, ak2, N);
    aggregate2_kernel<<<agg_blocks, 256, 0, stream>>>(
        row_ptr, edges, t2, aq2, ak2, bmu, blv, Wm, bm, Wl, bl, out_mu, out_ls,
        N);
  } else {
    // ---- sequential fallback (round-2 structure) ----
    transform_kernel<64><<<dim3(R, tiles256), 256, 0, stream>>>(
        hidden, Wmu, qmu, kmu, t2, aq2, ak2, N);
    aggregate_kernel<<<agg_blocks, 256, 0, stream>>>(row_ptr, edges, t2, aq2,
                                                     ak2, bmu, fmu, N);
    transform_kernel<64><<<dim3(R, tiles256), 256, 0, stream>>>(
        hidden, Wlv, qlv, klv, t2, aq2, ak2, N);
    aggregate_kernel<<<agg_blocks, 256, 0, stream>>>(row_ptr, edges, t2, aq2,
                                                     ak2, blv, flv, N);
    const int lin_blocks = (N * ODIM + 255) / 256;
    linear_kernel<<<lin_blocks, 256, 0, stream>>>(fmu, Wm, bm, out_mu, 1.0f, N);
    linear_kernel<<<lin_blocks, 256, 0, stream>>>(flv, Wl, bl, out_ls, 0.5f, N);
  }
}